// Round 8
// baseline (164.861 us; speedup 1.0000x reference)
//
#include <hip/hip_runtime.h>
#include <math.h>

// B=8, C=128, N=4096, d=16, groups=32
// R24 = gnprep+qkv VERBATIM (VT2/K2 fragment-major) + attn: per-wave PRIVATE
//   LDS staging, exact asm-counted vmcnt, ZERO barriers in loop.
//   Ledger: barrier-per-tile variants ~70-71 (R16/R20/R23); uncoupled 63-67
//   (R17/R21/R22) flat vs bytes(2x), blocks(2x), depth attempts. All pipes
//   <45%. Hypothesis: compiler waitcnt serialization -- VGPR-destined
//   prefetch forces compiler-placed waits; if vmcnt(0) (or load sinking,
//   proven R21) each iter waits on its OWN prefetch: per-tile = L2-loaded
//   latency (~1800cy) + compute (~500) = 2360cy measured. Fix: gl_lds DMA
//   (no VGPR dest -> nothing to sink) into per-wave private 2x9KB buffers,
//   s_waitcnt vmcnt(9) mine and exact (all 9 loop vmem = gl_lds), no
//   cross-wave coupling. LDS reads lane*16 contiguous (conflict-free per
//   R23's 65K). 73.7KB -> 2 blocks/CU.
//   Predict: attn 35-48us (>=58 kills theory -> ablation round), VALUBusy
//   55-70, VGPR 90-115, conflicts ~65K, FETCH ~13.8MB, total ~125-140.

typedef short v8s __attribute__((ext_vector_type(8)));   // 8 bf16 = 4 VGPRs
typedef float v16f __attribute__((ext_vector_type(16))); // 32x32 acc

__device__ __forceinline__ unsigned short f2bf_rne(float f) {
  unsigned u = __float_as_uint(f);
  u += 0x7fffu + ((u >> 16) & 1u);
  return (unsigned short)(u >> 16);
}

__device__ __forceinline__ v8s mk8(unsigned a, unsigned b, unsigned c, unsigned d) {
  union { unsigned u[4]; v8s s; } x;
  x.u[0] = a; x.u[1] = b; x.u[2] = c; x.u[3] = d;
  return x.s;
}

// pack two fp32 -> dword of 2 bf16 (truncation) in ONE v_perm_b32
__device__ __forceinline__ unsigned pack_trunc(float hi, float lo) {
  return __builtin_amdgcn_perm(__float_as_uint(hi), __float_as_uint(lo), 0x07060302u);
}

// async 16B global -> LDS (DMA). LDS dest = uniform base + lane*16 (HW adds).
__device__ __forceinline__ void gl_lds16(const void* g, void* l) {
  __builtin_amdgcn_global_load_lds(
      (const __attribute__((address_space(1))) unsigned int*)g,
      (__attribute__((address_space(3))) unsigned int*)l, 16, 0, 0);
}

// fragment-major V: short index for element (n, c).  (as R23)
#define VT2(b, n, c) (((size_t)(b) * 64 + ((n) >> 6)) * 8192 + \
   ((((n) >> 5) & 1) * 8 + (((n) >> 4) & 1) * 4 + ((c) >> 5)) * 512 + \
   ((((n) >> 3) & 1) * 32 + ((c) & 31)) * 8 + ((n) & 7))

// fragment-major K: short index for element (n, d), d in 0..15.  (as R23)
#define K2(b, n, d) (((size_t)(b) * 64 + ((n) >> 6)) * 1024 + \
   ((((n) >> 5) & 1)) * 512 + (((d) >> 3) * 32 + ((n) & 31)) * 8 + ((d) & 7))

// ws byte offsets
#define WSB_MURS   0u
#define WSB_WCATB  4096u       // 160*128 bf16 = 40960
#define WSB_BCAT   49152u      // 160 f32
#define WSB_PWB    65536u      // 128*128 bf16 = 32768
#define WSB_QBF    131072u     // Q^T [B,16,N] bf16 = 1 MB
#define WSB_KBF    1310720u    // K fragment-major = 1 MB
#define WSB_VBF    2621440u    // 8 MB (fragment-major tiled)

// ---------------------------------------------------------------------------
// gn_stats + prep fused. Grid 256 x 512 thr.  (VERBATIM)
// ---------------------------------------------------------------------------
__global__ __launch_bounds__(512)
void gnprep_kernel(const float* __restrict__ x, float* __restrict__ mu_rs,
                   const float* __restrict__ qw, const float* __restrict__ qb,
                   const float* __restrict__ kw, const float* __restrict__ kb,
                   const float* __restrict__ vw, const float* __restrict__ vb,
                   const float* __restrict__ pw,
                   unsigned short* __restrict__ wcatb, float* __restrict__ bcat,
                   unsigned short* __restrict__ pwb) {
  const int id = blockIdx.x;
  {
    const float qs = 0.36067376022224085f;  // 0.25 * log2(e)
    int idx = id * 512 + threadIdx.x;
    if (idx < 160 * 128) {
      int o = idx >> 7, c = idx & 127;
      float val;
      if (o < 16)       val = qw[o * 128 + c] * qs;
      else if (o < 32)  val = kw[(o - 16) * 128 + c];
      else              val = vw[(o - 32) * 128 + c];
      wcatb[idx] = f2bf_rne(val);
    } else if (idx < 160 * 128 + 160) {
      int o = idx - 160 * 128;
      bcat[o] = (o < 16) ? qb[o] * qs : (o < 32) ? kb[o - 16] : vb[o - 32];
    } else if (idx < 160 * 128 + 160 + 128 * 128) {
      int j = idx - (160 * 128 + 160);
      pwb[j] = f2bf_rne(pw[j]);
    }
  }
  const int bg = (id & 7) * 32 + (id >> 3);   // XCD swizzle: batch = id & 7
  const float4* xp = (const float4*)(x + (size_t)bg * 16384);
  float s = 0.f, ss = 0.f;
#pragma unroll
  for (int u = 0; u < 8; ++u) {
    int i = threadIdx.x + u * 512;
    float4 v = xp[i];
    s  += v.x + v.y + v.z + v.w;
    ss += v.x * v.x + v.y * v.y + v.z * v.z + v.w * v.w;
  }
  for (int off = 32; off > 0; off >>= 1) {
    s  += __shfl_down(s, off, 64);
    ss += __shfl_down(ss, off, 64);
  }
  __shared__ float red[16];
  int lane = threadIdx.x & 63, wid = threadIdx.x >> 6;
  if (lane == 0) { red[wid * 2] = s; red[wid * 2 + 1] = ss; }
  __syncthreads();
  if (threadIdx.x == 0) {
    float S = 0.f, SS = 0.f;
    for (int w = 0; w < 8; ++w) { S += red[w * 2]; SS += red[w * 2 + 1]; }
    float mu  = S * (1.0f / 16384.0f);
    float var = SS * (1.0f / 16384.0f) - mu * mu;
    float rs  = rsqrtf(var + 1e-5f);
    mu_rs[bg * 2]     = mu;
    mu_rs[bg * 2 + 1] = rs;
  }
}

// ---------------------------------------------------------------------------
// QKV: LDS-staged GEMM. (VERBATIM from R23, K/V stores in VT2/K2)
// ---------------------------------------------------------------------------
#define HS 136   // shorts per hs row (128 data + 8 pad); 16B-aligned rows

__global__ __launch_bounds__(512)
void qkv_kernel(const float* __restrict__ x, const float* __restrict__ gnw,
                const float* __restrict__ gnb, const float* __restrict__ mu_rs,
                const unsigned short* __restrict__ wcatb, const float* __restrict__ bcat,
                unsigned short* __restrict__ qTb, unsigned short* __restrict__ kbf,
                unsigned short* __restrict__ vbf) {
  __shared__ alignas(16) unsigned short hs[64 * HS];   // 17408 B
  __shared__ float scsh[128], shsh[128], bsh[160];
  const int id = blockIdx.x;
  const int b = id & 7, nb = (id >> 3) << 6;   // XCD-pinned batch
  const int t = threadIdx.x;
  const int w = t >> 6, lane = t & 63, h = lane >> 5, l = lane & 31;
  const int nsub = w & 1, og = w >> 1;

  if (t < 128) {
    float mu = mu_rs[(b * 32 + (t >> 2)) * 2];
    float rs = mu_rs[(b * 32 + (t >> 2)) * 2 + 1];
    float gw = gnw[t], gb = gnb[t];
    scsh[t] = rs * gw; shsh[t] = gb - mu * rs * gw;
  }
  if (t < 160) bsh[t] = bcat[t];
  __syncthreads();

  // ---- stage: thread = (sn = t&63, c-quad base c00 = (t>>6)*4), 4 iters ----
  const int sn = t & 63;
  const int c00 = (t >> 6) * 4;
  const float* xb = x + ((size_t)b * 128 << 12) + nb + sn;
#pragma unroll
  for (int it = 0; it < 4; ++it) {
    const int c0 = c00 + it * 32;    // wave-uniform
    float f0 = xb[(size_t)(c0)     << 12] * scsh[c0]     + shsh[c0];
    float f1 = xb[(size_t)(c0 + 1) << 12] * scsh[c0 + 1] + shsh[c0 + 1];
    float f2 = xb[(size_t)(c0 + 2) << 12] * scsh[c0 + 2] + shsh[c0 + 2];
    float f3 = xb[(size_t)(c0 + 3) << 12] * scsh[c0 + 3] + shsh[c0 + 3];
    uint2 u;
    u.x = (unsigned)f2bf_rne(f0) | ((unsigned)f2bf_rne(f1) << 16);
    u.y = (unsigned)f2bf_rne(f2) | ((unsigned)f2bf_rne(f3) << 16);
    *(uint2*)(&hs[sn * HS + c0]) = u;
  }
  __syncthreads();

  // ---- MFMA: wave (nsub, og); og0 -> ot{0,1}, og1..3 -> ot{2..4} ----
  const int n = nb + nsub * 32 + l;
  const int otbase = (og == 0) ? 0 : og + 1;
  v16f acc[2];
#pragma unroll
  for (int a2 = 0; a2 < 2; ++a2)
#pragma unroll
    for (int r = 0; r < 16; ++r) acc[a2][r] = 0.f;

#pragma unroll
  for (int ks = 0; ks < 8; ++ks) {
    v8s bf = *(const v8s*)(&hs[(nsub * 32 + l) * HS + ks * 16 + 8 * h]);
    {
      v8s af = *(const v8s*)(wcatb + (otbase * 32 + l) * 128 + ks * 16 + 8 * h);
      acc[0] = __builtin_amdgcn_mfma_f32_32x32x16_bf16(af, bf, acc[0], 0, 0, 0);
    }
    if (og == 0) {
      v8s af = *(const v8s*)(wcatb + (32 + l) * 128 + ks * 16 + 8 * h);
      acc[1] = __builtin_amdgcn_mfma_f32_32x32x16_bf16(af, bf, acc[1], 0, 0, 0);
    }
  }

  // ---- epilogue (K/V stores in fragment-major layouts) ----
  if (og == 0) {
#pragma unroll
    for (int r = 0; r < 16; ++r) {
      int o = 4 * h + (r & 3) + 8 * (r >> 2);
      unsigned short bv = f2bf_rne(acc[0][r] + bsh[o]);
      if (o < 16) qTb[((size_t)(b * 16 + o) << 12) + n] = bv;
      else        kbf[K2(b, n, o - 16)] = bv;
    }
#pragma unroll
    for (int r = 0; r < 16; ++r) {
      int o = 32 + 4 * h + (r & 3) + 8 * (r >> 2);
      vbf[VT2(b, n, o - 32)] = f2bf_rne(acc[1][r] + bsh[o]);
    }
  } else {
#pragma unroll
    for (int r = 0; r < 16; ++r) {
      int o = otbase * 32 + 4 * h + (r & 3) + 8 * (r >> 2);
      vbf[VT2(b, n, o - 32)] = f2bf_rne(acc[0][r] + bsh[o]);
    }
  }
}

// ---------------------------------------------------------------------------
// R24 flash attention + fused proj: 4 waves (jsub, ihalf); per-wave PRIVATE
// double-buffered LDS staging via gl_lds DMA, exact asm vmcnt(9), zero
// barriers in the loop. Grid 512 x 256 thr.
// ---------------------------------------------------------------------------
#define OTS 136                   // O^T row stride in shorts (68 dwords)
#define WBUF 9216                 // bytes per wave buffer: V 8K (own jsub) + K 1K

__global__ __launch_bounds__(256)
void attn_kernel(const unsigned short* __restrict__ qTb,
                 const unsigned short* __restrict__ kbf,
                 const unsigned short* __restrict__ vbf,
                 const unsigned short* __restrict__ pwb,
                 const float* __restrict__ pb,
                 const float* __restrict__ x,
                 float* __restrict__ out) {
  // 4 waves x 2 x 9216B private staging; epilogue overlays the front
  __shared__ alignas(16) unsigned char smem[4 * 2 * WBUF];   // 73728 B
  __shared__ float l_lds[64];
  __shared__ float pbs[128];

  const int id = blockIdx.x;
  const int b = id & 7, i0 = (id >> 3) << 6;   // XCD-pinned batch, 64-i tile
  const int t = threadIdx.x;
  const int w = t >> 6, lane = t & 63, h = lane >> 5, l = lane & 31;
  const int jsub = w & 1, ihalf = w >> 1;

  // global sources (fragment-major): own jsub's 8 V frags are contiguous 8KB
  const char* vsrc = (const char*)vbf + ((size_t)b << 20) + jsub * 8192 + lane * 16;
  const char* ksrc = (const char*)kbf + ((size_t)b * 131072) + jsub * 1024 + lane * 16;
  char* const mybase = (char*)smem + w * (2 * WBUF);

  if (t < 128) pbs[t] = pb[t];
  if (t < 64) l_lds[t] = 0.f;

  // Q B-frag from Q^T [B,16,N]: 8 coalesced b16 loads, once per kernel
  const int iglob = i0 + ihalf * 32 + l;
  unsigned qd[4];
#pragma unroll
  for (int e = 0; e < 4; ++e) {
    unsigned lo = qTb[((size_t)(b * 16 + 8 * h + 2 * e) << 12) + iglob];
    unsigned hi = qTb[((size_t)(b * 16 + 8 * h + 2 * e + 1) << 12) + iglob];
    qd[e] = lo | (hi << 16);
  }
  const v8s qf = mk8(qd[0], qd[1], qd[2], qd[3]);

  v16f zc;
#pragma unroll
  for (int r = 0; r < 16; ++r) zc[r] = 0.f;
  v16f acc[4];
#pragma unroll
  for (int ct = 0; ct < 4; ++ct)
#pragma unroll
    for (int r = 0; r < 16; ++r) acc[ct][r] = 0.f;
  float ls0 = 0.f, ls1 = 0.f, ls2 = 0.f, ls3 = 0.f;

  __syncthreads();   // l_lds zeros visible; also isolates prologue staging

  // stage tile TS's own-wave data (9 gl_lds) into buffer (TS)&1
#define STAGE_OWN(TS) {                                              \
    const int ts_ = (TS) & 63;                                       \
    char* dst_ = mybase + ((TS) & 1) * WBUF;                         \
    const char* vs_ = vsrc + (size_t)ts_ * 16384;                    \
    _Pragma("unroll") for (int f = 0; f < 8; ++f)                    \
      gl_lds16(vs_ + f * 1024, dst_ + f * 1024);                     \
    gl_lds16(ksrc + (size_t)ts_ * 2048, dst_ + 8192);                \
  }

  STAGE_OWN(0);   // after barrier: stays in flight, counted below

  for (int tile = 0; tile < 64; ++tile) {
    STAGE_OWN(tile + 1);   // prefetch next (wrap harmless)

    // exact: 18 outstanding -> wait until <=9 (the 9 newest = prefetch group
    // stay in flight through the whole tile body). No barrier, no coupling.
    asm volatile("s_waitcnt vmcnt(9)" ::: "memory");
    __builtin_amdgcn_sched_barrier(0);

    const unsigned short* bp =
        (const unsigned short*)(mybase + (tile & 1) * WBUF);

    // QK: K frag from own LDS (contiguous lane*16, conflict-free)
    v8s kf = *(const v8s*)(bp + 4096 + lane * 8);
    v16f st = __builtin_amdgcn_mfma_f32_32x32x16_bf16(kf, qf, zc, 0, 0, 0);
    float pe[16];
#pragma unroll
    for (int r = 0; r < 16; ++r) pe[r] = __builtin_amdgcn_exp2f(st[r]);
    ls0 += pe[0] + pe[4] + pe[8]  + pe[12];
    ls1 += pe[1] + pe[5] + pe[9]  + pe[13];
    ls2 += pe[2] + pe[6] + pe[10] + pe[14];
    ls3 += pe[3] + pe[7] + pe[11] + pe[15];
    unsigned G[8];
#pragma unroll
    for (int g = 0; g < 4; ++g) {
      G[2 * g]     = pack_trunc(pe[4 * g + 1], pe[4 * g]);
      G[2 * g + 1] = pack_trunc(pe[4 * g + 3], pe[4 * g + 2]);
    }
    // half-wave exchange via v_permlane32_swap_b32 (pure VALU; proven)
    unsigned A0 = G[0], B0 = G[2], A1 = G[1], B1 = G[3];
    unsigned A2 = G[4], B2 = G[6], A3 = G[5], B3 = G[7];
    asm("v_permlane32_swap_b32 %0, %1" : "+v"(A0), "+v"(B0));
    asm("v_permlane32_swap_b32 %0, %1" : "+v"(A1), "+v"(B1));
    asm("v_permlane32_swap_b32 %0, %1" : "+v"(A2), "+v"(B2));
    asm("v_permlane32_swap_b32 %0, %1" : "+v"(A3), "+v"(B3));
    v8s pf0 = mk8(A0, A1, B0, B1);
    v8s pf1 = mk8(A2, A3, B2, B3);

    // PV: own-jsub V frags from own LDS (contiguous, conflict-free)
    __builtin_amdgcn_s_setprio(1);
#pragma unroll
    for (int ct = 0; ct < 4; ++ct) {
      v8s vf0 = *(const v8s*)(bp + ct * 512 + lane * 8);
      v8s vf1 = *(const v8s*)(bp + (4 + ct) * 512 + lane * 8);
      acc[ct] = __builtin_amdgcn_mfma_f32_32x32x16_bf16(vf0, pf0, acc[ct], 0, 0, 0);
      acc[ct] = __builtin_amdgcn_mfma_f32_32x32x16_bf16(vf1, pf1, acc[ct], 0, 0, 0);
    }
    __builtin_amdgcn_s_setprio(0);
  }

  // ---- epilogue: jsub combine, then fused proj (verbatim) ----
  atomicAdd(&l_lds[ihalf * 32 + l], (ls0 + ls1) + (ls2 + ls3));
  __syncthreads();   // full drain (leftover DMA lands) + l complete

  float* const ov = (float*)smem;   // f32 combine overlay
  if (jsub == 1) {
#pragma unroll
    for (int ct = 0; ct < 4; ++ct)
#pragma unroll
      for (int q = 0; q < 4; ++q) {
        float4 v4 = {acc[ct][4 * q], acc[ct][4 * q + 1],
                     acc[ct][4 * q + 2], acc[ct][4 * q + 3]};
        *(float4*)&ov[((ct * 2 + ihalf) * 32 + l) * 36 + 4 * h + 8 * q] = v4;
      }
  }
  __syncthreads();
  if (jsub == 0) {
#pragma unroll
    for (int ct = 0; ct < 4; ++ct)
#pragma unroll
      for (int q = 0; q < 4; ++q) {
        float4 v4 = *(float4*)&ov[((ct * 2 + ihalf) * 32 + l) * 36 + 4 * h + 8 * q];
        acc[ct][4 * q]     += v4.x;
        acc[ct][4 * q + 1] += v4.y;
        acc[ct][4 * q + 2] += v4.z;
        acc[ct][4 * q + 3] += v4.w;
      }
  }
  __syncthreads();   // ov reads complete; smem reusable

  // jsub=0 waves write normalized O^T bf16 [n_local][c], stride OTS
  unsigned short* const oT = (unsigned short*)smem;
  if (jsub == 0) {
    const float li = 1.f / l_lds[ihalf * 32 + l];
    const int nrow = ihalf * 32 + l;
#pragma unroll
    for (int ct = 0; ct < 4; ++ct)
#pragma unroll
      for (int r = 0; r < 16; r += 2) {
        int c = ct * 32 + 4 * h + (r & 3) + 8 * (r >> 2);   // even
        unsigned dw = (unsigned)f2bf_rne(acc[ct][r] * li) |
                      ((unsigned)f2bf_rne(acc[ct][r + 1] * li) << 16);
        *(unsigned*)(&oT[nrow * OTS + c]) = dw;
      }
  }
  __syncthreads();

  // fused proj: wave w -> e-tile w (32 e), both n-subs. out = pw@O + pb + x.
#pragma unroll
  for (int nsub = 0; nsub < 2; ++nsub) {
    v16f a2;
#pragma unroll
    for (int r = 0; r < 16; ++r) a2[r] = 0.f;
#pragma unroll
    for (int ks = 0; ks < 8; ++ks) {
      v8s bf = *(const v8s*)(&oT[(nsub * 32 + l) * OTS + ks * 16 + 8 * h]);
      v8s af = *(const v8s*)(pwb + (w * 32 + l) * 128 + ks * 16 + 8 * h);
      a2 = __builtin_amdgcn_mfma_f32_32x32x16_bf16(af, bf, a2, 0, 0, 0);
    }
    const int n = i0 + nsub * 32 + l;
#pragma unroll
    for (int r = 0; r < 16; ++r) {
      int e = w * 32 + 4 * h + (r & 3) + 8 * (r >> 2);
      size_t idx = ((size_t)(b * 128 + e) << 12) + n;
      out[idx] = a2[r] + pbs[e] + x[idx];
    }
  }
}

// ---------------------------------------------------------------------------
extern "C" void kernel_launch(void* const* d_in, const int* in_sizes, int n_in,
                              void* d_out, int out_size, void* d_ws, size_t ws_size,
                              hipStream_t stream) {
  const float* x   = (const float*)d_in[0];
  const float* gnw = (const float*)d_in[1];
  const float* gnb = (const float*)d_in[2];
  const float* qw  = (const float*)d_in[3];
  const float* qb  = (const float*)d_in[4];
  const float* kw  = (const float*)d_in[5];
  const float* kb  = (const float*)d_in[6];
  const float* vw  = (const float*)d_in[7];
  const float* vb  = (const float*)d_in[8];
  const float* pw  = (const float*)d_in[9];
  const float* pb  = (const float*)d_in[10];
  float* out = (float*)d_out;
  char* ws = (char*)d_ws;

  float* mu_rs = (float*)(ws + WSB_MURS);
  unsigned short* wcatb = (unsigned short*)(ws + WSB_WCATB);
  float* bcat = (float*)(ws + WSB_BCAT);
  unsigned short* pwb = (unsigned short*)(ws + WSB_PWB);
  unsigned short* qTb = (unsigned short*)(ws + WSB_QBF);
  unsigned short* kbf = (unsigned short*)(ws + WSB_KBF);
  unsigned short* vbf = (unsigned short*)(ws + WSB_VBF);

  hipLaunchKernelGGL(gnprep_kernel, dim3(256), dim3(512), 0, stream,
                     x, mu_rs, qw, qb, kw, kb, vw, vb, pw, wcatb, bcat, pwb);
  hipLaunchKernelGGL(qkv_kernel, dim3(512), dim3(512), 0, stream,
                     x, gnw, gnb, mu_rs, wcatb, bcat, qTb, kbf, vbf);
  hipLaunchKernelGGL(attn_kernel, dim3(512), dim3(256), 0, stream,
                     qTb, kbf, vbf, pwb, pb, x, out);
}

// Round 9
// 153.200 us; speedup vs baseline: 1.0761x; 1.0761x over previous
//
#include <hip/hip_runtime.h>
#include <math.h>

// B=8, C=128, N=4096, d=16, groups=32
// R25 = gnprep VERBATIM + attn = R17 VERBATIM (measured 63us best; 5 attn
//   structural hypotheses failed: waves/blocks/depth/bytes/DMA all 63-81us,
//   attn parked) + qkv epilogue rewritten for coalesced stores.
//   Ledger: total 153 - attn 63 = ~90us NOT attn. gnprep ~5us by
//   construction. qkv suspect: 32 scattered 2B global stores/thread
//   (8.4M store instrs, ~8 lines touched per wave-store, L2 write-allocate
//   RMW). All three output regions per block are CONTIGUOUS in global
//   (Q 2KB, K 2KB, V 16KB in VT layout) -> stage through 20KB LDS obuf in
//   target layout (2B LDS writes, <=4-way), barrier, uint4 coalesced
//   copy-out (160 wave-instrs/block). LDS 39.5KB -> 4 blocks/CU.
//   Predict: attn 63-64 (VGPR ~120, conflicts ~65K = clean revert);
//   total 153 -> 105-130. Pre-commit: total >=145 => qkv-store theory
//   wrong -> probe launch/harness overhead next, not stores.

typedef short v8s __attribute__((ext_vector_type(8)));   // 8 bf16 = 4 VGPRs
typedef float v16f __attribute__((ext_vector_type(16))); // 32x32 acc

__device__ __forceinline__ unsigned short f2bf_rne(float f) {
  unsigned u = __float_as_uint(f);
  u += 0x7fffu + ((u >> 16) & 1u);
  return (unsigned short)(u >> 16);
}

__device__ __forceinline__ v8s mk8(unsigned a, unsigned b, unsigned c, unsigned d) {
  union { unsigned u[4]; v8s s; } x;
  x.u[0] = a; x.u[1] = b; x.u[2] = c; x.u[3] = d;
  return x.s;
}

// pack two fp32 -> dword of 2 bf16 (truncation) in ONE v_perm_b32
__device__ __forceinline__ unsigned pack_trunc(float hi, float lo) {
  return __builtin_amdgcn_perm(__float_as_uint(hi), __float_as_uint(lo), 0x07060302u);
}

// tiled V element index: [b][j>>4][c][j&15]  (ORIGINAL layout, as R17)
#define VT(b, n, c) (((((size_t)(b) * 256 + ((n) >> 4)) << 7) + (c)) * 16 + ((n) & 15))

// ws byte offsets
#define WSB_MURS   0u
#define WSB_WCATB  4096u       // 160*128 bf16 = 40960
#define WSB_BCAT   49152u      // 160 f32
#define WSB_PWB    65536u      // 128*128 bf16 = 32768
#define WSB_QBF    131072u     // Q^T [B,16,N] bf16 = 1 MB
#define WSB_KBF    1310720u    // K [B,N,16] bf16 = 1 MB
#define WSB_VBF    2621440u    // 8 MB (tiled)

// ---------------------------------------------------------------------------
// gn_stats + prep fused. Grid 256 x 512 thr.  (VERBATIM)
// ---------------------------------------------------------------------------
__global__ __launch_bounds__(512)
void gnprep_kernel(const float* __restrict__ x, float* __restrict__ mu_rs,
                   const float* __restrict__ qw, const float* __restrict__ qb,
                   const float* __restrict__ kw, const float* __restrict__ kb,
                   const float* __restrict__ vw, const float* __restrict__ vb,
                   const float* __restrict__ pw,
                   unsigned short* __restrict__ wcatb, float* __restrict__ bcat,
                   unsigned short* __restrict__ pwb) {
  const int id = blockIdx.x;
  {
    const float qs = 0.36067376022224085f;  // 0.25 * log2(e)
    int idx = id * 512 + threadIdx.x;
    if (idx < 160 * 128) {
      int o = idx >> 7, c = idx & 127;
      float val;
      if (o < 16)       val = qw[o * 128 + c] * qs;
      else if (o < 32)  val = kw[(o - 16) * 128 + c];
      else              val = vw[(o - 32) * 128 + c];
      wcatb[idx] = f2bf_rne(val);
    } else if (idx < 160 * 128 + 160) {
      int o = idx - 160 * 128;
      bcat[o] = (o < 16) ? qb[o] * qs : (o < 32) ? kb[o - 16] : vb[o - 32];
    } else if (idx < 160 * 128 + 160 + 128 * 128) {
      int j = idx - (160 * 128 + 160);
      pwb[j] = f2bf_rne(pw[j]);
    }
  }
  const int bg = (id & 7) * 32 + (id >> 3);   // XCD swizzle: batch = id & 7
  const float4* xp = (const float4*)(x + (size_t)bg * 16384);
  float s = 0.f, ss = 0.f;
#pragma unroll
  for (int u = 0; u < 8; ++u) {
    int i = threadIdx.x + u * 512;
    float4 v = xp[i];
    s  += v.x + v.y + v.z + v.w;
    ss += v.x * v.x + v.y * v.y + v.z * v.z + v.w * v.w;
  }
  for (int off = 32; off > 0; off >>= 1) {
    s  += __shfl_down(s, off, 64);
    ss += __shfl_down(ss, off, 64);
  }
  __shared__ float red[16];
  int lane = threadIdx.x & 63, wid = threadIdx.x >> 6;
  if (lane == 0) { red[wid * 2] = s; red[wid * 2 + 1] = ss; }
  __syncthreads();
  if (threadIdx.x == 0) {
    float S = 0.f, SS = 0.f;
    for (int w = 0; w < 8; ++w) { S += red[w * 2]; SS += red[w * 2 + 1]; }
    float mu  = S * (1.0f / 16384.0f);
    float var = SS * (1.0f / 16384.0f) - mu * mu;
    float rs  = rsqrtf(var + 1e-5f);
    mu_rs[bg * 2]     = mu;
    mu_rs[bg * 2 + 1] = rs;
  }
}

// ---------------------------------------------------------------------------
// QKV: LDS-staged GEMM; compute/stage VERBATIM; epilogue now LDS-staged
// coalesced stores (obuf in target layout -> uint4 copy-out).
// ---------------------------------------------------------------------------
#define HS 136   // shorts per hs row (128 data + 8 pad); 16B-aligned rows

__global__ __launch_bounds__(512)
void qkv_kernel(const float* __restrict__ x, const float* __restrict__ gnw,
                const float* __restrict__ gnb, const float* __restrict__ mu_rs,
                const unsigned short* __restrict__ wcatb, const float* __restrict__ bcat,
                unsigned short* __restrict__ qTb, unsigned short* __restrict__ kbf,
                unsigned short* __restrict__ vbf) {
  __shared__ alignas(16) unsigned short hs[64 * HS];   // 17408 B
  __shared__ alignas(16) unsigned short obuf[10240];   // 20480 B out-stage
  __shared__ float scsh[128], shsh[128], bsh[160];
  const int id = blockIdx.x;
  const int b = id & 7, nb = (id >> 3) << 6;   // XCD-pinned batch
  const int t = threadIdx.x;
  const int w = t >> 6, lane = t & 63, h = lane >> 5, l = lane & 31;
  const int nsub = w & 1, og = w >> 1;

  if (t < 128) {
    float mu = mu_rs[(b * 32 + (t >> 2)) * 2];
    float rs = mu_rs[(b * 32 + (t >> 2)) * 2 + 1];
    float gw = gnw[t], gb = gnb[t];
    scsh[t] = rs * gw; shsh[t] = gb - mu * rs * gw;
  }
  if (t < 160) bsh[t] = bcat[t];
  __syncthreads();

  // ---- stage: thread = (sn = t&63, c-quad base c00 = (t>>6)*4), 4 iters ----
  const int sn = t & 63;
  const int c00 = (t >> 6) * 4;
  const float* xb = x + ((size_t)b * 128 << 12) + nb + sn;
#pragma unroll
  for (int it = 0; it < 4; ++it) {
    const int c0 = c00 + it * 32;    // wave-uniform
    float f0 = xb[(size_t)(c0)     << 12] * scsh[c0]     + shsh[c0];
    float f1 = xb[(size_t)(c0 + 1) << 12] * scsh[c0 + 1] + shsh[c0 + 1];
    float f2 = xb[(size_t)(c0 + 2) << 12] * scsh[c0 + 2] + shsh[c0 + 2];
    float f3 = xb[(size_t)(c0 + 3) << 12] * scsh[c0 + 3] + shsh[c0 + 3];
    uint2 u;
    u.x = (unsigned)f2bf_rne(f0) | ((unsigned)f2bf_rne(f1) << 16);
    u.y = (unsigned)f2bf_rne(f2) | ((unsigned)f2bf_rne(f3) << 16);
    *(uint2*)(&hs[sn * HS + c0]) = u;
  }
  __syncthreads();

  // ---- MFMA: wave (nsub, og); og0 -> ot{0,1}, og1..3 -> ot{2..4} ----
  const int nloc = nsub * 32 + l;     // local n in [0,64)
  const int otbase = (og == 0) ? 0 : og + 1;
  v16f acc[2];
#pragma unroll
  for (int a2 = 0; a2 < 2; ++a2)
#pragma unroll
    for (int r = 0; r < 16; ++r) acc[a2][r] = 0.f;

#pragma unroll
  for (int ks = 0; ks < 8; ++ks) {
    v8s bf = *(const v8s*)(&hs[nloc * HS + ks * 16 + 8 * h]);
    {
      v8s af = *(const v8s*)(wcatb + (otbase * 32 + l) * 128 + ks * 16 + 8 * h);
      acc[0] = __builtin_amdgcn_mfma_f32_32x32x16_bf16(af, bf, acc[0], 0, 0, 0);
    }
    if (og == 0) {
      v8s af = *(const v8s*)(wcatb + (32 + l) * 128 + ks * 16 + 8 * h);
      acc[1] = __builtin_amdgcn_mfma_f32_32x32x16_bf16(af, bf, acc[1], 0, 0, 0);
    }
  }

  // ---- epilogue: write acc fragments to obuf in TARGET layout ----
  // obuf shorts: [0,1024) Q rows o*64+nloc; [1024,2048) K nloc*16+dd;
  //              [2048,10240) V (nloc>>4)*2048 + c*16 + (nloc&15)
  if (og == 0) {
#pragma unroll
    for (int r = 0; r < 16; ++r) {
      int o = 4 * h + (r & 3) + 8 * (r >> 2);              // 0..31
      unsigned short bv = f2bf_rne(acc[0][r] + bsh[o]);
      if (o < 16) obuf[o * 64 + nloc] = bv;
      else        obuf[1024 + nloc * 16 + (o - 16)] = bv;
    }
#pragma unroll
    for (int r = 0; r < 16; ++r) {
      int o = 32 + 4 * h + (r & 3) + 8 * (r >> 2);         // c = o-32 in 0..31
      obuf[2048 + (nloc >> 4) * 2048 + (o - 32) * 16 + (nloc & 15)] =
          f2bf_rne(acc[1][r] + bsh[o]);
    }
  } else {
#pragma unroll
    for (int r = 0; r < 16; ++r) {
      int o = otbase * 32 + 4 * h + (r & 3) + 8 * (r >> 2); // c = o-32 in 32..127
      obuf[2048 + (nloc >> 4) * 2048 + (o - 32) * 16 + (nloc & 15)] =
          f2bf_rne(acc[0][r] + bsh[o]);
    }
  }
  __syncthreads();

  // ---- coalesced copy-out: all regions contiguous in global ----
  if (t < 128) {          // Q: 16 rows x 64 shorts (128B/row)
    int o = t >> 3, off = (t & 7) * 8;
    *(uint4*)(qTb + ((size_t)(b * 16 + o) << 12) + nb + off) =
        *(const uint4*)(obuf + o * 64 + off);
  } else if (t < 256) {   // K: 1024 shorts contiguous
    int j2 = t - 128;
    *(uint4*)(kbf + (((size_t)b * 4096 + nb) << 4) + j2 * 8) =
        *(const uint4*)(obuf + 1024 + j2 * 8);
  }
  {                       // V: 8192 shorts contiguous (VT region of this tile)
    unsigned short* vdst = vbf + (((size_t)b * 256 + (nb >> 4)) << 11);
#pragma unroll
    for (int it2 = 0; it2 < 2; ++it2) {
      int idx = t + it2 * 512;
      *(uint4*)(vdst + idx * 8) = *(const uint4*)(obuf + 2048 + idx * 8);
    }
  }
}

// ---------------------------------------------------------------------------
// R17 flash attention + fused proj (VERBATIM: measured 63us).
// Grid 512 x 256 thr (4 waves: jsub = w&1, ihalf = w>>1).
// ---------------------------------------------------------------------------
#define OTS 136                   // O^T row stride in shorts (68 dwords)

__global__ __launch_bounds__(256)
void attn_kernel(const unsigned short* __restrict__ qTb,
                 const unsigned short* __restrict__ kbf,
                 const unsigned short* __restrict__ vbf,
                 const unsigned short* __restrict__ pwb,
                 const float* __restrict__ pb,
                 const float* __restrict__ x,
                 float* __restrict__ out) {
  // epilogue-only LDS: f32 combine overlay (36864 B) reused as O^T bf16
  __shared__ alignas(16) float ovs[9216];
  __shared__ float l_lds[64];
  __shared__ float pbs[128];

  const int id = blockIdx.x;
  const int b = id & 7, i0 = (id >> 3) << 6;   // XCD-pinned batch, 64-i tile
  const int t = threadIdx.x;
  const int w = t >> 6, lane = t & 63, h = lane >> 5, l = lane & 31;
  const int jsub = w & 1, ihalf = w >> 1;

  // per-lane base pointers (fragment-coalesced: lane(h,l) at byte l*32+h*16)
  const unsigned short* kg = kbf + ((size_t)b << 16) + jsub * 512 + l * 16 + 8 * h;
  const unsigned short* vg = vbf + ((size_t)b << 19) + jsub * 4096 + l * 16 + 8 * h;

  if (t < 128) pbs[t] = pb[t];
  if (t < 64) l_lds[t] = 0.f;

  // Q B-frag from Q^T [B,16,N]: 8 coalesced b16 loads, once per kernel
  const int iglob = i0 + ihalf * 32 + l;
  unsigned qd[4];
#pragma unroll
  for (int e = 0; e < 4; ++e) {
    unsigned lo = qTb[((size_t)(b * 16 + 8 * h + 2 * e) << 12) + iglob];
    unsigned hi = qTb[((size_t)(b * 16 + 8 * h + 2 * e + 1) << 12) + iglob];
    qd[e] = lo | (hi << 16);
  }
  const v8s qf = mk8(qd[0], qd[1], qd[2], qd[3]);

  v16f zc;
#pragma unroll
  for (int r = 0; r < 16; ++r) zc[r] = 0.f;
  v16f acc[4];
#pragma unroll
  for (int ct = 0; ct < 4; ++ct)
#pragma unroll
    for (int r = 0; r < 16; ++r) acc[ct][r] = 0.f;
  float ls = 0.f;

  __syncthreads();   // l_lds zeros visible before any epilogue atomicAdd

  // prologue: tile-0 K frag + 8 V frags into regs
  v8s kf = *(const v8s*)kg;
  v8s vf[8];
#pragma unroll
  for (int ct = 0; ct < 4; ++ct) {
    vf[2 * ct]     = *(const v8s*)(vg + ct * 512);
    vf[2 * ct + 1] = *(const v8s*)(vg + 2048 + ct * 512);
  }

#pragma unroll 2
  for (int tile = 0; tile < 64; ++tile) {
    const int tn = (tile + 1) & 63;   // wrap: harmless reload on last iter

    // issue next-tile loads FIRST; latency hidden under QK + softmax + PV
    v8s kn = *(const v8s*)(kg + (size_t)tn * 1024);
    v8s vn[8];
    const unsigned short* vt = vg + (size_t)tn * 8192;
#pragma unroll
    for (int ct = 0; ct < 4; ++ct) {
      vn[2 * ct]     = *(const v8s*)(vt + ct * 512);
      vn[2 * ct + 1] = *(const v8s*)(vt + 2048 + ct * 512);
    }

    // QK: S^T patch (rows j, cols i) -> P in regs
    v16f st = __builtin_amdgcn_mfma_f32_32x32x16_bf16(kf, qf, zc, 0, 0, 0);
    float pe[16];
#pragma unroll
    for (int r = 0; r < 16; ++r) { pe[r] = __builtin_amdgcn_exp2f(st[r]); ls += pe[r]; }
    unsigned G[8];
#pragma unroll
    for (int g = 0; g < 4; ++g) {
      G[2 * g]     = pack_trunc(pe[4 * g + 1], pe[4 * g]);
      G[2 * g + 1] = pack_trunc(pe[4 * g + 3], pe[4 * g + 2]);
    }
    // half-wave exchange (proven mapping): 4 shfl + selects
    unsigned S0 = h ? G[0] : G[2], S1 = h ? G[1] : G[3];
    unsigned S2 = h ? G[4] : G[6], S3 = h ? G[5] : G[7];
    unsigned R0 = (unsigned)__shfl_xor((int)S0, 32, 64);
    unsigned R1 = (unsigned)__shfl_xor((int)S1, 32, 64);
    unsigned R2 = (unsigned)__shfl_xor((int)S2, 32, 64);
    unsigned R3 = (unsigned)__shfl_xor((int)S3, 32, 64);
    v8s pf0 = h ? mk8(R0, R1, G[2], G[3]) : mk8(G[0], G[1], R0, R1);
    v8s pf1 = h ? mk8(R2, R3, G[6], G[7]) : mk8(G[4], G[5], R2, R3);

    // PV on current-tile register fragments (no LDS, no barrier)
#pragma unroll
    for (int ct = 0; ct < 4; ++ct) {
      acc[ct] = __builtin_amdgcn_mfma_f32_32x32x16_bf16(vf[2 * ct],     pf0, acc[ct], 0, 0, 0);
      acc[ct] = __builtin_amdgcn_mfma_f32_32x32x16_bf16(vf[2 * ct + 1], pf1, acc[ct], 0, 0, 0);
    }

    // rotate prefetch (copies vanish under unroll-2 renaming)
    kf = kn;
#pragma unroll
    for (int u = 0; u < 8; ++u) vf[u] = vn[u];
  }

  // ---- epilogue: jsub combine, then fused proj ----
  atomicAdd(&l_lds[ihalf * 32 + l], ls);
  __syncthreads();   // l complete; ovs free

  float* const ov = ovs;   // f32 combine overlay
  if (jsub == 1) {
#pragma unroll
    for (int ct = 0; ct < 4; ++ct)
#pragma unroll
      for (int q = 0; q < 4; ++q) {
        float4 v4 = {acc[ct][4 * q], acc[ct][4 * q + 1],
                     acc[ct][4 * q + 2], acc[ct][4 * q + 3]};
        *(float4*)&ov[((ct * 2 + ihalf) * 32 + l) * 36 + 4 * h + 8 * q] = v4;
      }
  }
  __syncthreads();
  if (jsub == 0) {
#pragma unroll
    for (int ct = 0; ct < 4; ++ct)
#pragma unroll
      for (int q = 0; q < 4; ++q) {
        float4 v4 = *(float4*)&ov[((ct * 2 + ihalf) * 32 + l) * 36 + 4 * h + 8 * q];
        acc[ct][4 * q]     += v4.x;
        acc[ct][4 * q + 1] += v4.y;
        acc[ct][4 * q + 2] += v4.z;
        acc[ct][4 * q + 3] += v4.w;
      }
  }
  __syncthreads();   // ov reads complete; overlay reusable

  // jsub=0 waves write normalized O^T bf16 [n_local][c], stride OTS
  unsigned short* const oT = (unsigned short*)ovs;
  if (jsub == 0) {
    const float li = 1.f / l_lds[ihalf * 32 + l];
    const int nrow = ihalf * 32 + l;
#pragma unroll
    for (int ct = 0; ct < 4; ++ct)
#pragma unroll
      for (int r = 0; r < 16; r += 2) {
        int c = ct * 32 + 4 * h + (r & 3) + 8 * (r >> 2);   // even
        unsigned dw = (unsigned)f2bf_rne(acc[ct][r] * li) |
                      ((unsigned)f2bf_rne(acc[ct][r + 1] * li) << 16);
        *(unsigned*)(&oT[nrow * OTS + c]) = dw;
      }
  }
  __syncthreads();

  // fused proj: wave w -> e-tile w (32 e), both n-subs. out = pw@O + pb + x.
#pragma unroll
  for (int nsub = 0; nsub < 2; ++nsub) {
    v16f a2;
#pragma unroll
    for (int r = 0; r < 16; ++r) a2[r] = 0.f;
#pragma unroll
    for (int ks = 0; ks < 8; ++ks) {
      v8s bf = *(const v8s*)(&oT[(nsub * 32 + l) * OTS + ks * 16 + 8 * h]);
      v8s af = *(const v8s*)(pwb + (w * 32 + l) * 128 + ks * 16 + 8 * h);
      a2 = __builtin_amdgcn_mfma_f32_32x32x16_bf16(af, bf, a2, 0, 0, 0);
    }
    const int n = i0 + nsub * 32 + l;
#pragma unroll
    for (int r = 0; r < 16; ++r) {
      int e = w * 32 + 4 * h + (r & 3) + 8 * (r >> 2);
      size_t idx = ((size_t)(b * 128 + e) << 12) + n;
      out[idx] = a2[r] + pbs[e] + x[idx];
    }
  }
}

// ---------------------------------------------------------------------------
extern "C" void kernel_launch(void* const* d_in, const int* in_sizes, int n_in,
                              void* d_out, int out_size, void* d_ws, size_t ws_size,
                              hipStream_t stream) {
  const float* x   = (const float*)d_in[0];
  const float* gnw = (const float*)d_in[1];
  const float* gnb = (const float*)d_in[2];
  const float* qw  = (const float*)d_in[3];
  const float* qb  = (const float*)d_in[4];
  const float* kw  = (const float*)d_in[5];
  const float* kb  = (const float*)d_in[6];
  const float* vw  = (const float*)d_in[7];
  const float* vb  = (const float*)d_in[8];
  const float* pw  = (const float*)d_in[9];
  const float* pb  = (const float*)d_in[10];
  float* out = (float*)d_out;
  char* ws = (char*)d_ws;

  float* mu_rs = (float*)(ws + WSB_MURS);
  unsigned short* wcatb = (unsigned short*)(ws + WSB_WCATB);
  float* bcat = (float*)(ws + WSB_BCAT);
  unsigned short* pwb = (unsigned short*)(ws + WSB_PWB);
  unsigned short* qTb = (unsigned short*)(ws + WSB_QBF);
  unsigned short* kbf = (unsigned short*)(ws + WSB_KBF);
  unsigned short* vbf = (unsigned short*)(ws + WSB_VBF);

  hipLaunchKernelGGL(gnprep_kernel, dim3(256), dim3(512), 0, stream,
                     x, mu_rs, qw, qb, kw, kb, vw, vb, pw, wcatb, bcat, pwb);
  hipLaunchKernelGGL(qkv_kernel, dim3(512), dim3(512), 0, stream,
                     x, gnw, gnb, mu_rs, wcatb, bcat, qTb, kbf, vbf);
  hipLaunchKernelGGL(attn_kernel, dim3(512), dim3(256), 0, stream,
                     qTb, kbf, vbf, pwb, pb, x, out);
}